// Round 2
// baseline (2056.664 us; speedup 1.0000x reference)
//
#include <hip/hip_runtime.h>

namespace {
constexpr int kB = 16;
constexpr int kN = 8732;
constexpr int kC = 20;
constexpr int kRow = 25;      // 1 + C + 4
constexpr int kKeep = 300;    // NNS_K
constexpr int kTot = 200;     // K_TOTAL
constexpr float kConf = 0.01f;
// fl32(inter/union) > 0.45f  <=>  inter/union > 0.45f + ulp/2 (0.45f mantissa even,
// tie rounds down). kThr = 30198989 * 2^-26 exactly:
constexpr double kThr = 0.45000000298023223876953125;

constexpr int TPB1 = 512;
constexpr int EPT1 = 18;      // 512*18 = 9216 >= 8732
constexpr int NW1 = TPB1 / 64;

constexpr int kFlat = kC * kKeep;  // 6000
constexpr int kChunk = 94;         // ceil(6000/64)
constexpr int kPad = 129;          // 129 % 32 == 1 -> conflict-free chunk writes
}

// One block per (b, c) task: iterative-argmax greedy NMS.
// Per iteration: [pair-reduce already maintained by sweep] -> B1 -> owner
// publishes box -> B2 -> fused sweep (suppress + zap-selected + (max,idx)).
// No global traffic inside the loop (so barriers don't drain vmcnt on stores).
__global__ __launch_bounds__(TPB1, 2) void nms_kernel(const float* __restrict__ in,
                                                      float* __restrict__ ws_s,
                                                      float* __restrict__ ws_b) {
  const int task = blockIdx.x;
  const int b = task / kC;
  const int c = task - b * kC;
  const int tid = threadIdx.x;
  const int lane = tid & 63;
  const int wid = tid >> 6;

  const float* __restrict__ base = in + (size_t)b * kN * kRow;

  float sc[EPT1], by1[EPT1], bx1[EPT1], by2[EPT1], bx2[EPT1], bar[EPT1];
#pragma unroll
  for (int k = 0; k < EPT1; ++k) {
    const int n = tid + k * TPB1;
    if (n < kN) {
      const float* r = base + (size_t)n * kRow;
      const float s = r[1 + c];
      by1[k] = r[21]; bx1[k] = r[22]; by2[k] = r[23]; bx2[k] = r[24];
      bar[k] = __fmul_rn(__fsub_rn(by2[k], by1[k]), __fsub_rn(bx2[k], bx1[k]));
      sc[k] = (s > kConf) ? s : -1.0f;
    } else {
      by1[k] = bx1[k] = by2[k] = bx2[k] = bar[k] = 0.0f;
      sc[k] = -1.0f;
    }
  }

  __shared__ float s_ps[NW1];
  __shared__ unsigned s_pn[NW1];
  __shared__ float s_box[5];          // y1,x1,y2,x2,area of selected
  __shared__ float sel_s_l[kKeep];
  __shared__ unsigned sel_n_l[kKeep];

  // initial per-thread (max, min-index) over own elements
  float lmax = -1.0f;
  unsigned lidx = 0;
#pragma unroll
  for (int k = 0; k < EPT1; ++k) {
    const bool up = sc[k] > lmax;        // strict > keeps min k (min n) on ties
    lmax = up ? sc[k] : lmax;
    lidx = up ? (unsigned)(tid + k * TPB1) : lidx;
  }

  int cnt = 0;
  for (;;) {
    // wave-level (score, min-index) butterfly reduce
    float bs = lmax;
    unsigned bn = lidx;
#pragma unroll
    for (int off = 32; off; off >>= 1) {
      const float os = __shfl_xor(bs, off);
      const unsigned on = __shfl_xor(bn, off);
      const bool take = (os > bs) || ((os == bs) && (on < bn));
      bs = take ? os : bs;
      bn = take ? on : bn;
    }
    if (lane == 0) { s_ps[wid] = bs; s_pn[wid] = bn; }
    __syncthreads();  // B1: pairs visible
    float smax = s_ps[0];
    unsigned sel = s_pn[0];
#pragma unroll
    for (int w = 1; w < NW1; ++w) {
      const float os = s_ps[w];
      const unsigned on = s_pn[w];
      const bool take = (os > smax) || ((os == smax) && (on < sel));
      smax = take ? os : smax;
      sel = take ? on : sel;
    }
    if (smax <= 0.0f || cnt >= kKeep) break;  // uniform across block
    if (tid == (int)(sel & (TPB1 - 1))) {
#pragma unroll
      for (int k = 0; k < EPT1; ++k) {
        if ((unsigned)(tid + k * TPB1) == sel) {
          s_box[0] = by1[k]; s_box[1] = bx1[k];
          s_box[2] = by2[k]; s_box[3] = bx2[k];
          s_box[4] = bar[k];
        }
      }
    }
    if (tid == 0) { sel_s_l[cnt] = smax; sel_n_l[cnt] = sel; }
    __syncthreads();  // B2: s_box visible
    const float sy1 = s_box[0], sx1 = s_box[1], sy2 = s_box[2], sx2 = s_box[3],
                sar = s_box[4];
    lmax = -1.0f;
    lidx = 0;
#pragma unroll
    for (int k = 0; k < EPT1; ++k) {
      const unsigned n = (unsigned)(tid + k * TPB1);
      const float ty1 = fmaxf(by1[k], sy1);
      const float tx1 = fmaxf(bx1[k], sx1);
      const float ty2 = fminf(by2[k], sy2);
      const float tx2 = fminf(bx2[k], sx2);
      const float dy = fmaxf(__fsub_rn(ty2, ty1), 0.0f);
      const float dx = fmaxf(__fsub_rn(tx2, tx1), 0.0f);
      const float inter = __fmul_rn(dy, dx);
      const float uni = __fsub_rn(__fadd_rn(sar, bar[k]), inter);
      // exact emulation of fl32(inter/uni) > 0.45f
      const bool supp = (uni > 0.0f) && ((double)inter > kThr * (double)uni);
      const bool kill = supp || (n == sel);
      sc[k] = kill ? -1.0f : sc[k];
      const bool up = sc[k] > lmax;
      lmax = up ? sc[k] : lmax;
      lidx = up ? n : lidx;
    }
    ++cnt;
  }

  // bulk write selected results (boxes re-read from input: bit-identical)
  float* __restrict__ out_s = ws_s + (size_t)task * kKeep;
  float* __restrict__ out_b = ws_b + (size_t)task * kKeep * 4;
  for (int i = tid; i < kKeep; i += TPB1) {
    if (i < cnt) {
      out_s[i] = sel_s_l[i];
      const float* r = base + (size_t)sel_n_l[i] * kRow;
      out_b[i * 4 + 0] = r[21];
      out_b[i * 4 + 1] = r[22];
      out_b[i * 4 + 2] = r[23];
      out_b[i * 4 + 3] = r[24];
    } else {
      out_s[i] = -1.0f;
    }
  }
}

// One wave per batch: stable top-200 (descending score, min flat-index ties),
// mirroring jax.lax.top_k. Incremental per-lane max; on removal only the
// owner lane's chunk is rescanned (all 64 lanes assist).
__global__ __launch_bounds__(64) void topk_kernel(const float* __restrict__ ws_s,
                                                  const float* __restrict__ ws_b,
                                                  float* __restrict__ out) {
  const int b = blockIdx.x;
  const int lane = threadIdx.x;
  const float* __restrict__ ss = ws_s + (size_t)b * kFlat;
  const float* __restrict__ bb = ws_b + (size_t)b * kFlat * 4;
  float* __restrict__ ob = out + (size_t)b * kTot * 6;

  __shared__ float lds[64 * kPad];

  // lane owns flat indices [lane*94, lane*94+94) at LDS slots [lane*129, ...)
  float lmax = -2.0f;
  unsigned lidx = 0;
  for (int i = 0; i < kChunk; ++i) {
    const int f = lane * kChunk + i;
    const float v = (f < kFlat) ? ss[f] : -2.0f;
    const unsigned slot = (unsigned)(lane * kPad + i);
    lds[slot] = v;
    const bool up = v > lmax;
    lmax = up ? v : lmax;
    lidx = up ? slot : lidx;
  }
  for (int i = kChunk; i < kPad; ++i) lds[lane * kPad + i] = -2.0f;
  __syncthreads();

  int r = 0;
  for (; r < kTot; ++r) {
    // butterfly (score, min-slot) reduce; slot order == flat order
    float bs = lmax;
    unsigned bn = lidx;
#pragma unroll
    for (int off = 32; off; off >>= 1) {
      const float os = __shfl_xor(bs, off);
      const unsigned on = __shfl_xor(bn, off);
      const bool take = (os > bs) || ((os == bs) && (on < bn));
      bs = take ? os : bs;
      bn = take ? on : bn;
    }
    if (bs <= 0.0f) break;  // only empty(-1)/pad(-2) remain
    const unsigned gslot = bn;
    const unsigned owner = gslot / kPad;
    const unsigned f = owner * kChunk + (gslot - owner * kPad);

    // box fetch (uniform address; loads overlap the rescan below)
    const float q0 = bb[f * 4 + 0];
    const float q1 = bb[f * 4 + 1];
    const float q2 = bb[f * 4 + 2];
    const float q3 = bb[f * 4 + 3];

    // remove selected, rescan owner chunk (all lanes assist)
    if (lane == 0) lds[gslot] = -2.0f;
    __syncthreads();
    const unsigned baseo = owner * kPad;
    float ns = -2.0f;
    unsigned nn = 0;
#pragma unroll
    for (int j = 0; j < 2; ++j) {
      const unsigned idx = baseo + j * 64 + lane;  // < baseo + 128 <= baseo + kPad-1
      const float v = lds[idx];
      const bool up = v > ns;
      ns = up ? v : ns;
      nn = up ? idx : nn;
    }
#pragma unroll
    for (int off = 32; off; off >>= 1) {
      const float os = __shfl_xor(ns, off);
      const unsigned on = __shfl_xor(nn, off);
      const bool take = (os > ns) || ((os == ns) && (on < nn));
      ns = take ? os : ns;
      nn = take ? on : nn;
    }
    if (lane == (int)owner) { lmax = ns; lidx = nn; }

    if (lane == 0) {
      const unsigned cls = f / kKeep;  // 0..19
      ob[r * 6 + 0] = (float)(cls + 1);
      ob[r * 6 + 1] = bs;
      ob[r * 6 + 2] = fminf(fmaxf(q0, 0.0f), 1.0f);
      ob[r * 6 + 3] = fminf(fmaxf(q1, 0.0f), 1.0f);
      ob[r * 6 + 4] = fminf(fmaxf(q2, 0.0f), 1.0f);
      ob[r * 6 + 5] = fminf(fmaxf(q3, 0.0f), 1.0f);
    }
    __syncthreads();
  }
  // invalid rows: class = 0+1 = 1, score 0, boxes 0
  for (int idx = r * 6 + lane; idx < kTot * 6; idx += 64) {
    ob[idx] = ((idx % 6) == 0) ? 1.0f : 0.0f;
  }
}

extern "C" void kernel_launch(void* const* d_in, const int* in_sizes, int n_in,
                              void* d_out, int out_size, void* d_ws, size_t ws_size,
                              hipStream_t stream) {
  const float* in = (const float*)d_in[0];
  float* out = (float*)d_out;
  float* ws_s = (float*)d_ws;                    // 320*300 floats
  float* ws_b = ws_s + (size_t)kB * kC * kKeep;  // 320*300*4 floats
  nms_kernel<<<dim3(kB * kC), dim3(TPB1), 0, stream>>>(in, ws_s, ws_b);
  topk_kernel<<<dim3(kB), dim3(64), 0, stream>>>(ws_s, ws_b, out);
}

// Round 3
// 1858.437 us; speedup vs baseline: 1.1067x; 1.1067x over previous
//
#include <hip/hip_runtime.h>

namespace {
constexpr int kB = 16;
constexpr int kN = 8732;
constexpr int kC = 20;
constexpr int kRow = 25;      // 1 + C + 4
constexpr int kKeep = 300;    // NNS_K
constexpr int kTot = 200;     // K_TOTAL
constexpr float kConf = 0.01f;
// fl32(inter/union) > 0.45f  <=>  inter/union > 0.45f + ulp/2 (0.45f mantissa even,
// tie rounds down). kThr = 30198989 * 2^-26 exactly; 26-bit x 24-bit product
// is <= 50 bits -> exact in f64, so the f64 compare is an exact emulation.
constexpr double kThr = 0.45000000298023223876953125;

constexpr int TPB1 = 512;
constexpr int EPT1 = 18;      // 512*18 = 9216 >= 8732
constexpr int NW1 = TPB1 / 64;

constexpr int kFlat = kC * kKeep;  // 6000
constexpr int kChunk = 94;         // ceil(6000/64)
constexpr int kPad = 129;          // 129 % 32 == 1 -> conflict-free chunk writes
}

// One block per (b, c) task: iterative-argmax greedy NMS.
// __launch_bounds__(512, 4): 4 waves/EU min -> VGPR cap 128 -> 2 blocks/CU ->
// all 320 blocks co-resident (no two-phase dispatch tail).
__global__ __launch_bounds__(TPB1, 4) void nms_kernel(const float* __restrict__ in,
                                                      float* __restrict__ ws_s,
                                                      float* __restrict__ ws_b) {
  const int task = blockIdx.x;
  const int b = task / kC;
  const int c = task - b * kC;
  const int tid = threadIdx.x;
  const int lane = tid & 63;
  const int wid = tid >> 6;

  const float* __restrict__ base = in + (size_t)b * kN * kRow;

  float sc[EPT1], by1[EPT1], bx1[EPT1], by2[EPT1], bx2[EPT1], bar[EPT1];
#pragma unroll
  for (int k = 0; k < EPT1; ++k) {
    const int n = tid + k * TPB1;
    if (n < kN) {
      const float* r = base + (size_t)n * kRow;
      const float s = r[1 + c];
      by1[k] = r[21]; bx1[k] = r[22]; by2[k] = r[23]; bx2[k] = r[24];
      bar[k] = __fmul_rn(__fsub_rn(by2[k], by1[k]), __fsub_rn(bx2[k], bx1[k]));
      sc[k] = (s > kConf) ? s : -1.0f;
    } else {
      by1[k] = bx1[k] = by2[k] = bx2[k] = bar[k] = 0.0f;
      sc[k] = -1.0f;
    }
  }

  __shared__ float s_ps[NW1];
  __shared__ unsigned s_pn[NW1];
  __shared__ float s_box[5];          // y1,x1,y2,x2,area of selected
  __shared__ float sel_s_l[kKeep];
  __shared__ unsigned sel_n_l[kKeep];

  // initial per-thread (max, min-index) over own elements
  float lmax = -1.0f;
  unsigned lidx = 0;
#pragma unroll
  for (int k = 0; k < EPT1; ++k) {
    const bool up = sc[k] > lmax;        // strict > keeps min k (min n) on ties
    lmax = up ? sc[k] : lmax;
    lidx = up ? (unsigned)(tid + k * TPB1) : lidx;
  }

  int cnt = 0;
  for (;;) {
    // wave-level (score, min-index) butterfly reduce
    float bs = lmax;
    unsigned bn = lidx;
#pragma unroll
    for (int off = 32; off; off >>= 1) {
      const float os = __shfl_xor(bs, off);
      const unsigned on = __shfl_xor(bn, off);
      const bool take = (os > bs) || ((os == bs) && (on < bn));
      bs = take ? os : bs;
      bn = take ? on : bn;
    }
    if (lane == 0) { s_ps[wid] = bs; s_pn[wid] = bn; }
    __syncthreads();  // B1: pairs visible
    float smax = s_ps[0];
    unsigned sel = s_pn[0];
#pragma unroll
    for (int w = 1; w < NW1; ++w) {
      const float os = s_ps[w];
      const unsigned on = s_pn[w];
      const bool take = (os > smax) || ((os == smax) && (on < sel));
      smax = take ? os : smax;
      sel = take ? on : sel;
    }
    if (smax <= 0.0f || cnt >= kKeep) break;  // uniform across block
    if (tid == (int)(sel & (TPB1 - 1))) {
#pragma unroll
      for (int k = 0; k < EPT1; ++k) {
        if ((unsigned)(tid + k * TPB1) == sel) {
          s_box[0] = by1[k]; s_box[1] = bx1[k];
          s_box[2] = by2[k]; s_box[3] = bx2[k];
          s_box[4] = bar[k];
          sc[k] = -1.0f;    // owner-zap: removes selected from candidate set
        }
      }
    }
    if (tid == 0) { sel_s_l[cnt] = smax; sel_n_l[cnt] = sel; }
    __syncthreads();  // B2: s_box + owner-zap visible
    const float sy1 = s_box[0], sx1 = s_box[1], sy2 = s_box[2], sx2 = s_box[3],
                sar = s_box[4];
    lmax = -1.0f;
    lidx = 0;
#pragma unroll
    for (int k = 0; k < EPT1; ++k) {
      const float ty1 = fmaxf(by1[k], sy1);
      const float tx1 = fmaxf(bx1[k], sx1);
      const float ty2 = fminf(by2[k], sy2);
      const float tx2 = fminf(bx2[k], sx2);
      const float dy = fmaxf(__fsub_rn(ty2, ty1), 0.0f);
      const float dx = fmaxf(__fsub_rn(tx2, tx1), 0.0f);
      const float inter = __fmul_rn(dy, dx);
      const float uni = __fsub_rn(__fadd_rn(sar, bar[k]), inter);
      // exact emulation of (uni>0) && fl32(inter/uni) > 0.45f:
      // uni >= 0 provably; uni==0 => inter==0 => compare false. So no guard.
      const bool supp = ((double)inter > kThr * (double)uni);
      sc[k] = supp ? -1.0f : sc[k];
      const bool up = sc[k] > lmax;
      lmax = up ? sc[k] : lmax;
      lidx = up ? (unsigned)(tid + k * TPB1) : lidx;
    }
    ++cnt;
  }

  // bulk write selected results (boxes re-read from input: bit-identical)
  float* __restrict__ out_s = ws_s + (size_t)task * kKeep;
  float* __restrict__ out_b = ws_b + (size_t)task * kKeep * 4;
  for (int i = tid; i < kKeep; i += TPB1) {
    if (i < cnt) {
      out_s[i] = sel_s_l[i];
      const float* r = base + (size_t)sel_n_l[i] * kRow;
      out_b[i * 4 + 0] = r[21];
      out_b[i * 4 + 1] = r[22];
      out_b[i * 4 + 2] = r[23];
      out_b[i * 4 + 3] = r[24];
    } else {
      out_s[i] = -1.0f;
    }
  }
}

// One wave per batch: stable top-200 (descending score, min flat-index ties),
// mirroring jax.lax.top_k. Incremental per-lane max; on removal only the
// owner lane's chunk is rescanned (all 64 lanes assist).
__global__ __launch_bounds__(64) void topk_kernel(const float* __restrict__ ws_s,
                                                  const float* __restrict__ ws_b,
                                                  float* __restrict__ out) {
  const int b = blockIdx.x;
  const int lane = threadIdx.x;
  const float* __restrict__ ss = ws_s + (size_t)b * kFlat;
  const float* __restrict__ bb = ws_b + (size_t)b * kFlat * 4;
  float* __restrict__ ob = out + (size_t)b * kTot * 6;

  __shared__ float lds[64 * kPad];

  // lane owns flat indices [lane*94, lane*94+94) at LDS slots [lane*129, ...)
  float lmax = -2.0f;
  unsigned lidx = 0;
  for (int i = 0; i < kChunk; ++i) {
    const int f = lane * kChunk + i;
    const float v = (f < kFlat) ? ss[f] : -2.0f;
    const unsigned slot = (unsigned)(lane * kPad + i);
    lds[slot] = v;
    const bool up = v > lmax;
    lmax = up ? v : lmax;
    lidx = up ? slot : lidx;
  }
  for (int i = kChunk; i < kPad; ++i) lds[lane * kPad + i] = -2.0f;
  __syncthreads();

  int r = 0;
  for (; r < kTot; ++r) {
    // butterfly (score, min-slot) reduce; slot order == flat order
    float bs = lmax;
    unsigned bn = lidx;
#pragma unroll
    for (int off = 32; off; off >>= 1) {
      const float os = __shfl_xor(bs, off);
      const unsigned on = __shfl_xor(bn, off);
      const bool take = (os > bs) || ((os == bs) && (on < bn));
      bs = take ? os : bs;
      bn = take ? on : bn;
    }
    if (bs <= 0.0f) break;  // only empty(-1)/pad(-2) remain
    const unsigned gslot = bn;
    const unsigned owner = gslot / kPad;
    const unsigned f = owner * kChunk + (gslot - owner * kPad);

    // box fetch (uniform address; loads overlap the rescan below)
    const float q0 = bb[f * 4 + 0];
    const float q1 = bb[f * 4 + 1];
    const float q2 = bb[f * 4 + 2];
    const float q3 = bb[f * 4 + 3];

    // remove selected, rescan owner chunk (all lanes assist)
    if (lane == 0) lds[gslot] = -2.0f;
    __syncthreads();
    const unsigned baseo = owner * kPad;
    float ns = -2.0f;
    unsigned nn = 0;
#pragma unroll
    for (int j = 0; j < 2; ++j) {
      const unsigned idx = baseo + j * 64 + lane;  // < baseo + 128 <= baseo + kPad-1
      const float v = lds[idx];
      const bool up = v > ns;
      ns = up ? v : ns;
      nn = up ? idx : nn;
    }
#pragma unroll
    for (int off = 32; off; off >>= 1) {
      const float os = __shfl_xor(ns, off);
      const unsigned on = __shfl_xor(nn, off);
      const bool take = (os > ns) || ((os == ns) && (on < nn));
      ns = take ? os : ns;
      nn = take ? on : nn;
    }
    if (lane == (int)owner) { lmax = ns; lidx = nn; }

    if (lane == 0) {
      const unsigned cls = f / kKeep;  // 0..19
      ob[r * 6 + 0] = (float)(cls + 1);
      ob[r * 6 + 1] = bs;
      ob[r * 6 + 2] = fminf(fmaxf(q0, 0.0f), 1.0f);
      ob[r * 6 + 3] = fminf(fmaxf(q1, 0.0f), 1.0f);
      ob[r * 6 + 4] = fminf(fmaxf(q2, 0.0f), 1.0f);
      ob[r * 6 + 5] = fminf(fmaxf(q3, 0.0f), 1.0f);
    }
    __syncthreads();
  }
  // invalid rows: class = 0+1 = 1, score 0, boxes 0
  for (int idx = r * 6 + lane; idx < kTot * 6; idx += 64) {
    ob[idx] = ((idx % 6) == 0) ? 1.0f : 0.0f;
  }
}

extern "C" void kernel_launch(void* const* d_in, const int* in_sizes, int n_in,
                              void* d_out, int out_size, void* d_ws, size_t ws_size,
                              hipStream_t stream) {
  const float* in = (const float*)d_in[0];
  float* out = (float*)d_out;
  float* ws_s = (float*)d_ws;                    // 320*300 floats
  float* ws_b = ws_s + (size_t)kB * kC * kKeep;  // 320*300*4 floats
  nms_kernel<<<dim3(kB * kC), dim3(TPB1), 0, stream>>>(in, ws_s, ws_b);
  topk_kernel<<<dim3(kB), dim3(64), 0, stream>>>(ws_s, ws_b, out);
}